// Round 2
// baseline (1033.776 us; speedup 1.0000x reference)
//
#include <hip/hip_runtime.h>
#include <math.h>

#define NSITE 100
#define NOCC  50
#define DIM   128
#define KDET  4

// readlane of a double via two 32-bit readlanes (p is wave-uniform)
__device__ __forceinline__ double readlane_d(double v, int p) {
  int lo = __builtin_amdgcn_readlane(__double2loint(v), p);
  int hi = __builtin_amdgcn_readlane(__double2hiint(v), p);
  return __hiloint2double(hi, lo);
}

// One block per (batch, spin). Wave w handles determinant k=w.
// Lane r owns row r of phi (in registers) for r < 50.
__global__ __launch_bounds__(256) void det_kernel(
    const int*   __restrict__ configs,   // (B,100) int32
    const float* __restrict__ tok,       // (4,128)
    const float* __restrict__ pos,       // (144,128)
    const float* __restrict__ W,         // (400,128)
    const float* __restrict__ bvec,      // (400,)
    double*      __restrict__ dets)      // (B,2,4,2)  {logdet, sign}
{
  const int b    = blockIdx.x;
  const int spin = blockIdx.y;

  __shared__ int cfg[NSITE];
  __shared__ int idx[NOCC];
  __shared__ int occl[NOCC];
  __shared__ int filll[NOCC];
  __shared__ int perm[4][NOCC];

  const int tid = threadIdx.x;
  if (tid < NSITE) cfg[tid] = configs[(size_t)b * NSITE + tid];
  __syncthreads();

  // Occupied-index list per reference argsort semantics: all occupied sites
  // (ascending, capped 50) + smallest unoccupied fill, merged sorted.
  if (tid == 0) {
    int no = 0, nf = 0;
    for (int n = 0; n < NSITE; ++n) {
      int c = cfg[n];
      bool occ = (spin == 0) ? (c == 1 || c == 3) : (c == 2 || c == 3);
      if (occ) { if (no < NOCC) occl[no++]  = n; }
      else     { if (nf < NOCC) filll[nf++] = n; }
    }
    int need = NOCC - no; if (need < 0) need = 0;
    int i = 0, j = 0;
    for (int k = 0; k < NOCC; ++k) {
      bool takeocc = (i < no) && (j >= need || occl[i] < filll[j]);
      idx[k] = takeocc ? occl[i++] : filll[j++];
    }
  }
  __syncthreads();

  const int lane = tid & 63;
  const int wave = tid >> 6;
  const int wave_u  = __builtin_amdgcn_readfirstlane(wave);
  const int colbase = spin * 200 + wave_u * 50;          // uniform
  const float* Wb = W    + (size_t)colbase * DIM;        // uniform base -> s_load
  const float* bb = bvec + colbase;

  const int  r   = lane;
  const bool act = (r < NOCC);
  const int  site = idx[act ? r : 0];
  const int  c    = cfg[site];
  const float4* tok4 = (const float4*)(tok + (size_t)c    * DIM);
  const float4* pos4 = (const float4*)(pos + (size_t)site * DIM);

  // ---- GEMM (fp64 accumulate): row r of phi_k = h . W[colbase+j] + b ----
  double row[NOCC];
  #pragma unroll 5
  for (int jt = 0; jt < 5; ++jt) {
    double acc[10];
    #pragma unroll
    for (int jj = 0; jj < 10; ++jj) acc[jj] = (double)bb[jt * 10 + jj];
    for (int d4 = 0; d4 < DIM / 4; ++d4) {
      float4 t = tok4[d4], p = pos4[d4];
      double a0 = (double)t.x + (double)p.x;
      double a1 = (double)t.y + (double)p.y;
      double a2 = (double)t.z + (double)p.z;
      double a3 = (double)t.w + (double)p.w;
      #pragma unroll
      for (int jj = 0; jj < 10; ++jj) {
        float4 w = ((const float4*)(Wb + (size_t)(jt * 10 + jj) * DIM))[d4];
        acc[jj] = fma(a0, (double)w.x, acc[jj]);
        acc[jj] = fma(a1, (double)w.y, acc[jj]);
        acc[jj] = fma(a2, (double)w.z, acc[jj]);
        acc[jj] = fma(a3, (double)w.w, acc[jj]);
      }
    }
    #pragma unroll
    for (int jj = 0; jj < 10; ++jj)
      row[jt * 10 + jj] = act ? acc[jj] : 0.0;
  }

  // ---- LU with implicit partial pivoting, rows register-resident ----
  double logdet = 0.0;
  int neg = 0;
  int mystep = -1;
  unsigned alive = act ? 1u : 0u;

  #pragma unroll
  for (int j = 0; j < NOCC; ++j) {
    // pivot key: |row[j]| high-word (monotonic for abs), low 6 bits = lane
    unsigned hi  = (unsigned)__double2hiint(fabs(row[j]));
    unsigned key = alive ? ((hi & ~63u) | (unsigned)lane) : 0u;
    #pragma unroll
    for (int m = 32; m >= 1; m >>= 1) {
      unsigned o = (unsigned)__shfl_xor((int)key, m, 64);
      key = key > o ? key : o;
    }
    const int p = __builtin_amdgcn_readfirstlane((int)(key & 63u));
    const double piv = readlane_d(row[j], p);
    logdet += log(fabs(piv));
    neg += (piv < 0.0) ? 1 : 0;
    if (lane == p) mystep = j;
    alive &= (lane != p) ? 1u : 0u;
    const double rp   = (piv != 0.0) ? 1.0 / piv : 0.0;
    const double mult = alive ? row[j] * rp : 0.0;
    #pragma unroll
    for (int cc = j + 1; cc < NOCC; ++cc) {
      const double pc = readlane_d(row[cc], p);
      row[cc] = fma(-mult, pc, row[cc]);
    }
  }

  // permutation parity: perm[step] = lane chosen at that step
  if (mystep >= 0) perm[wave][mystep] = lane;
  __syncthreads();
  int pj  = perm[wave][act ? lane : 0];
  int inv = 0;
  for (int i = 0; i < NOCC; ++i) {
    int pi = perm[wave][i];
    inv += (act && i < lane && pi > pj) ? 1 : 0;
  }
  #pragma unroll
  for (int m = 32; m >= 1; m >>= 1) inv += __shfl_xor(inv, m, 64);

  const int sgn = ((neg + inv) & 1) ? -1 : 1;
  if (lane == 0) {
    size_t o = (((size_t)b * 2 + spin) * KDET + wave) * 2;
    dets[o]     = logdet;
    dets[o + 1] = (double)sgn;
  }
}

// PLANAR complex64 output: out[0..B) = log_abs (real), out[B..2B) = phase (imag)
__global__ __launch_bounds__(256) void combine_kernel(
    const double* __restrict__ dets, float* __restrict__ out, int B)
{
  int b = blockIdx.x * blockDim.x + threadIdx.x;
  if (b >= B) return;
  const double* du = dets + ((size_t)b * 2 + 0) * KDET * 2;
  const double* dd = dets + ((size_t)b * 2 + 1) * KDET * 2;
  double t[KDET], s[KDET], m = -1e300;
  #pragma unroll
  for (int k = 0; k < KDET; ++k) {
    t[k] = du[2 * k] + dd[2 * k];
    s[k] = du[2 * k + 1] * dd[2 * k + 1];
    if (t[k] > m) m = t[k];
  }
  double sum = 0.0;
  #pragma unroll
  for (int k = 0; k < KDET; ++k) {
    if (t[k] > -1e290) sum += s[k] * exp(t[k] - m);
  }
  double p  = (m > -1e290) ? exp(m) * fabs(sum) : 0.0;
  double la = log(p + 1e-30);                    // reproduce ref clamp exactly
  float phase = (sum >= 0.0) ? 0.0f : 3.14159265358979f;
  out[b]     = (float)la;
  out[B + b] = phase;
}

extern "C" void kernel_launch(void* const* d_in, const int* in_sizes, int n_in,
                              void* d_out, int out_size, void* d_ws, size_t ws_size,
                              hipStream_t stream) {
  const int*   configs = (const int*)  d_in[0];
  const float* tok     = (const float*)d_in[1];
  const float* pos     = (const float*)d_in[2];
  const float* W       = (const float*)d_in[3];
  const float* bv      = (const float*)d_in[4];
  double* dets = (double*)d_ws;            // needs B*2*4*2*8 = 256 KB
  const int B = in_sizes[0] / NSITE;

  dim3 grid(B, 2);
  det_kernel<<<grid, 256, 0, stream>>>(configs, tok, pos, W, bv, dets);
  combine_kernel<<<(B + 255) / 256, 256, 0, stream>>>(dets, (float*)d_out, B);
}

// Round 3
// 906.307 us; speedup vs baseline: 1.1406x; 1.1406x over previous
//
#include <hip/hip_runtime.h>
#include <math.h>

#define NSITE 100
#define NOCC  50
#define DIM   128
#define KDET  4

// readlane of a double via two 32-bit readlanes (p is wave-uniform)
__device__ __forceinline__ double readlane_d(double v, int p) {
  int lo = __builtin_amdgcn_readlane(__double2loint(v), p);
  int hi = __builtin_amdgcn_readlane(__double2hiint(v), p);
  return __hiloint2double(hi, lo);
}

// One block per (batch, spin). Wave w handles determinant k=w.
// Lane r owns row r of phi entirely in registers (r < 50).
// __launch_bounds__(256,2): 2 waves/EU min -> 256-VGPR budget, so the
// 50-double row array (100 VGPRs) stays register-resident (R2 spilled at 68).
__global__ __launch_bounds__(256, 2) void det_kernel(
    const int*   __restrict__ configs,   // (B,100) int32
    const float* __restrict__ tok,       // (4,128)
    const float* __restrict__ pos,       // (144,128)
    const float* __restrict__ W,         // (400,128)
    const float* __restrict__ bvec,      // (400,)
    double*      __restrict__ dets)      // (B,2,4,2)  {logdet, sign}
{
  const int b    = blockIdx.x;
  const int spin = blockIdx.y;

  __shared__ int cfg[NSITE];
  __shared__ int idx[NOCC];
  __shared__ int occl[NOCC];
  __shared__ int filll[NOCC];
  __shared__ int perm[4][NOCC];

  const int tid = threadIdx.x;
  if (tid < NSITE) cfg[tid] = configs[(size_t)b * NSITE + tid];
  __syncthreads();

  // Occupied-index list per reference argsort semantics: all occupied sites
  // (ascending, capped 50) + smallest unoccupied fill, merged sorted.
  if (tid == 0) {
    int no = 0, nf = 0;
    for (int n = 0; n < NSITE; ++n) {
      int c = cfg[n];
      bool occ = (spin == 0) ? (c == 1 || c == 3) : (c == 2 || c == 3);
      if (occ) { if (no < NOCC) occl[no++]  = n; }
      else     { if (nf < NOCC) filll[nf++] = n; }
    }
    int need = NOCC - no; if (need < 0) need = 0;
    int i = 0, j = 0;
    for (int k = 0; k < NOCC; ++k) {
      bool takeocc = (i < no) && (j >= need || occl[i] < filll[j]);
      idx[k] = takeocc ? occl[i++] : filll[j++];
    }
  }
  __syncthreads();

  const int lane = tid & 63;
  const int wave = tid >> 6;
  const int wave_u  = __builtin_amdgcn_readfirstlane(wave);
  const int colbase = spin * 200 + wave_u * 50;          // uniform
  const float* Wb = W    + (size_t)colbase * DIM;        // uniform base
  const float* bb = bvec + colbase;

  const int  r   = lane;
  const bool act = (r < NOCC);
  const int  site = idx[act ? r : 0];
  const int  c    = cfg[site];
  const float4* tok4 = (const float4*)(tok + (size_t)c    * DIM);
  const float4* pos4 = (const float4*)(pos + (size_t)site * DIM);

  // ---- GEMM (fp64 accumulate): row r of phi_k = h . W[colbase+j] + b ----
  double row[NOCC];
  #pragma unroll 5
  for (int jt = 0; jt < 5; ++jt) {
    double acc[10];
    #pragma unroll
    for (int jj = 0; jj < 10; ++jj) acc[jj] = (double)bb[jt * 10 + jj];
    for (int d4 = 0; d4 < DIM / 4; ++d4) {
      float4 t = tok4[d4], p = pos4[d4];
      double a0 = (double)t.x + (double)p.x;
      double a1 = (double)t.y + (double)p.y;
      double a2 = (double)t.z + (double)p.z;
      double a3 = (double)t.w + (double)p.w;
      #pragma unroll
      for (int jj = 0; jj < 10; ++jj) {
        float4 w = ((const float4*)(Wb + (size_t)(jt * 10 + jj) * DIM))[d4];
        acc[jj] = fma(a0, (double)w.x, acc[jj]);
        acc[jj] = fma(a1, (double)w.y, acc[jj]);
        acc[jj] = fma(a2, (double)w.z, acc[jj]);
        acc[jj] = fma(a3, (double)w.w, acc[jj]);
      }
    }
    #pragma unroll
    for (int jj = 0; jj < 10; ++jj)
      row[jt * 10 + jj] = act ? acc[jj] : 0.0;
  }

  // ---- LU with implicit partial pivoting, rows register-resident ----
  // logdet via exponent-sum + mantissa-product (single log at the end).
  double mant_prod = 1.0;
  int    esum = 0;
  int    neg = 0;
  int    mystep = -1;
  unsigned alive = act ? 1u : 0u;

  #pragma unroll
  for (int j = 0; j < NOCC; ++j) {
    // pivot key: |row[j]| high-word (monotonic for abs), low 6 bits = lane
    unsigned hi  = (unsigned)__double2hiint(fabs(row[j]));
    unsigned key = alive ? ((hi & ~63u) | (unsigned)lane) : 0u;
    #pragma unroll
    for (int m = 32; m >= 1; m >>= 1) {
      unsigned o = (unsigned)__shfl_xor((int)key, m, 64);
      key = key > o ? key : o;
    }
    const int p = __builtin_amdgcn_readfirstlane((int)(key & 63u));
    const double piv = readlane_d(row[j], p);

    // decompose piv = sign * mant * 2^(e-1023), mant in [1,2)
    const unsigned phi_w = (unsigned)__double2hiint(piv);
    esum += (int)((phi_w >> 20) & 0x7ffu) - 1023;
    neg  += (int)(phi_w >> 31);
    mant_prod *= __hiloint2double((int)((phi_w & 0x000FFFFFu) | 0x3FF00000u),
                                  __double2loint(piv));

    if (lane == p) mystep = j;
    alive &= (lane != p) ? 1u : 0u;
    const double rp   = (piv != 0.0) ? 1.0 / piv : 0.0;
    const double mult = alive ? row[j] * rp : 0.0;
    #pragma unroll
    for (int cc = j + 1; cc < NOCC; ++cc) {
      const double pc = readlane_d(row[cc], p);
      row[cc] = fma(-mult, pc, row[cc]);
    }
  }

  // mant_prod in [1, 2^50): renormalize into logdet
  double logdet = log(mant_prod) + (double)esum * 0.6931471805599453;

  // permutation parity: perm[step] = lane chosen at that step
  if (mystep >= 0) perm[wave][mystep] = lane;
  __syncthreads();
  int pj  = perm[wave][act ? lane : 0];
  int inv = 0;
  for (int i = 0; i < NOCC; ++i) {
    int pi = perm[wave][i];
    inv += (act && i < lane && pi > pj) ? 1 : 0;
  }
  #pragma unroll
  for (int m = 32; m >= 1; m >>= 1) inv += __shfl_xor(inv, m, 64);

  const int sgn = ((neg + inv) & 1) ? -1 : 1;
  if (lane == 0) {
    size_t o = (((size_t)b * 2 + spin) * KDET + wave) * 2;
    dets[o]     = logdet;
    dets[o + 1] = (double)sgn;
  }
}

// PLANAR complex64 output: out[0..B) = log_abs (real), out[B..2B) = phase (imag)
__global__ __launch_bounds__(256) void combine_kernel(
    const double* __restrict__ dets, float* __restrict__ out, int B)
{
  int b = blockIdx.x * blockDim.x + threadIdx.x;
  if (b >= B) return;
  const double* du = dets + ((size_t)b * 2 + 0) * KDET * 2;
  const double* dd = dets + ((size_t)b * 2 + 1) * KDET * 2;
  double t[KDET], s[KDET], m = -1e300;
  #pragma unroll
  for (int k = 0; k < KDET; ++k) {
    t[k] = du[2 * k] + dd[2 * k];
    s[k] = du[2 * k + 1] * dd[2 * k + 1];
    if (t[k] > m) m = t[k];
  }
  double sum = 0.0;
  #pragma unroll
  for (int k = 0; k < KDET; ++k) {
    if (t[k] > -1e290) sum += s[k] * exp(t[k] - m);
  }
  double p  = (m > -1e290) ? exp(m) * fabs(sum) : 0.0;
  double la = log(p + 1e-30);                    // reproduce ref clamp exactly
  float phase = (sum >= 0.0) ? 0.0f : 3.14159265358979f;
  out[b]     = (float)la;
  out[B + b] = phase;
}

extern "C" void kernel_launch(void* const* d_in, const int* in_sizes, int n_in,
                              void* d_out, int out_size, void* d_ws, size_t ws_size,
                              hipStream_t stream) {
  const int*   configs = (const int*)  d_in[0];
  const float* tok     = (const float*)d_in[1];
  const float* pos     = (const float*)d_in[2];
  const float* W       = (const float*)d_in[3];
  const float* bv      = (const float*)d_in[4];
  double* dets = (double*)d_ws;            // needs B*2*4*2*8 = 256 KB
  const int B = in_sizes[0] / NSITE;

  dim3 grid(B, 2);
  det_kernel<<<grid, 256, 0, stream>>>(configs, tok, pos, W, bv, dets);
  combine_kernel<<<(B + 255) / 256, 256, 0, stream>>>(dets, (float*)d_out, B);
}

// Round 4
// 904.918 us; speedup vs baseline: 1.1424x; 1.0015x over previous
//
#include <hip/hip_runtime.h>
#include <math.h>

#define NSITE 100
#define NOCC  50
#define DIM   128
#define KDET  4

// readlane of a double via two 32-bit readlanes (p is wave-uniform)
__device__ __forceinline__ double readlane_d(double v, int p) {
  int lo = __builtin_amdgcn_readlane(__double2loint(v), p);
  int hi = __builtin_amdgcn_readlane(__double2hiint(v), p);
  return __hiloint2double(hi, lo);
}

// One LU pivot step with COMPILE-TIME step index J.
// Why templates: with a runtime j, the inner cc-loop has a runtime trip
// count -> LLVM can't fully unroll -> row[cc] is a dynamic index -> SROA
// can't promote row[] -> the whole array lives in scratch (R2/R3: VGPR=68,
// ~1275 scratch loads/lane, 906 us). Constexpr J makes every index a
// literal so row[] is register-resident.
template <int J>
struct LUStep {
  static __device__ __forceinline__ void run(double (&row)[NOCC], int lane,
      unsigned& alive, double& mant_prod, int& esum, int& neg, int& mystep) {
    // pivot key: |row[J]| high-word (monotonic for abs), low 6 bits = lane
    unsigned hi  = (unsigned)__double2hiint(fabs(row[J]));
    unsigned key = alive ? ((hi & ~63u) | (unsigned)lane) : 0u;
    #pragma unroll
    for (int m = 32; m >= 1; m >>= 1) {
      unsigned o = (unsigned)__shfl_xor((int)key, m, 64);
      key = key > o ? key : o;
    }
    const int p = __builtin_amdgcn_readfirstlane((int)(key & 63u));
    const double piv = readlane_d(row[J], p);

    // piv = sign * mant * 2^(e-1023): accumulate exponent, sign, mantissa
    const unsigned phiw = (unsigned)__double2hiint(piv);
    esum += (int)((phiw >> 20) & 0x7ffu) - 1023;
    neg  += (int)(phiw >> 31);
    mant_prod *= __hiloint2double((int)((phiw & 0x000FFFFFu) | 0x3FF00000u),
                                  __double2loint(piv));

    if (lane == p) mystep = J;
    alive &= (lane != p) ? 1u : 0u;
    const double rp   = (piv != 0.0) ? 1.0 / piv : 0.0;
    const double mult = alive ? row[J] * rp : 0.0;
    #pragma unroll
    for (int cc = J + 1; cc < NOCC; ++cc) {   // compile-time bounds
      const double pc = readlane_d(row[cc], p);
      row[cc] = fma(-mult, pc, row[cc]);
    }
    LUStep<J + 1>::run(row, lane, alive, mant_prod, esum, neg, mystep);
  }
};
template <>
struct LUStep<NOCC> {
  static __device__ __forceinline__ void run(double (&)[NOCC], int,
      unsigned&, double&, int&, int&, int&) {}
};

// One block per (batch, spin). Wave w handles determinant k=w.
// Lane r owns row r of phi entirely in registers (r < 50).
__global__ __launch_bounds__(256, 2) void det_kernel(
    const int*   __restrict__ configs,   // (B,100) int32
    const float* __restrict__ tok,       // (4,128)
    const float* __restrict__ pos,       // (144,128)
    const float* __restrict__ W,         // (400,128)
    const float* __restrict__ bvec,      // (400,)
    double*      __restrict__ dets)      // (B,2,4,2)  {logdet, sign}
{
  const int b    = blockIdx.x;
  const int spin = blockIdx.y;

  __shared__ int cfg[NSITE];
  __shared__ int idx[NOCC];
  __shared__ int occl[NOCC];
  __shared__ int filll[NOCC];
  __shared__ int perm[4][NOCC];

  const int tid = threadIdx.x;
  if (tid < NSITE) cfg[tid] = configs[(size_t)b * NSITE + tid];
  __syncthreads();

  // Occupied-index list per reference argsort semantics: all occupied sites
  // (ascending, capped 50) + smallest unoccupied fill, merged sorted.
  if (tid == 0) {
    int no = 0, nf = 0;
    for (int n = 0; n < NSITE; ++n) {
      int c = cfg[n];
      bool occ = (spin == 0) ? (c == 1 || c == 3) : (c == 2 || c == 3);
      if (occ) { if (no < NOCC) occl[no++]  = n; }
      else     { if (nf < NOCC) filll[nf++] = n; }
    }
    int need = NOCC - no; if (need < 0) need = 0;
    int i = 0, j = 0;
    for (int k = 0; k < NOCC; ++k) {
      bool takeocc = (i < no) && (j >= need || occl[i] < filll[j]);
      idx[k] = takeocc ? occl[i++] : filll[j++];
    }
  }
  __syncthreads();

  const int lane = tid & 63;
  const int wave = tid >> 6;
  const int wave_u  = __builtin_amdgcn_readfirstlane(wave);
  const int colbase = spin * 200 + wave_u * 50;          // uniform
  const float* Wb = W    + (size_t)colbase * DIM;        // uniform base
  const float* bb = bvec + colbase;

  const int  r   = lane;
  const bool act = (r < NOCC);
  const int  site = idx[act ? r : 0];
  const int  c    = cfg[site];
  const float4* tok4 = (const float4*)(tok + (size_t)c    * DIM);
  const float4* pos4 = (const float4*)(pos + (size_t)site * DIM);

  // ---- GEMM (fp64 accumulate): row r of phi_k = h . W[colbase+j] + b ----
  double row[NOCC];
  #pragma unroll 5
  for (int jt = 0; jt < 5; ++jt) {
    double acc[10];
    #pragma unroll
    for (int jj = 0; jj < 10; ++jj) acc[jj] = (double)bb[jt * 10 + jj];
    for (int d4 = 0; d4 < DIM / 4; ++d4) {
      float4 t = tok4[d4], p = pos4[d4];
      double a0 = (double)t.x + (double)p.x;
      double a1 = (double)t.y + (double)p.y;
      double a2 = (double)t.z + (double)p.z;
      double a3 = (double)t.w + (double)p.w;
      #pragma unroll
      for (int jj = 0; jj < 10; ++jj) {
        float4 w = ((const float4*)(Wb + (size_t)(jt * 10 + jj) * DIM))[d4];
        acc[jj] = fma(a0, (double)w.x, acc[jj]);
        acc[jj] = fma(a1, (double)w.y, acc[jj]);
        acc[jj] = fma(a2, (double)w.z, acc[jj]);
        acc[jj] = fma(a3, (double)w.w, acc[jj]);
      }
    }
    #pragma unroll
    for (int jj = 0; jj < 10; ++jj)
      row[jt * 10 + jj] = act ? acc[jj] : 0.0;
  }

  // ---- LU, register-resident, fully unrolled via template recursion ----
  double mant_prod = 1.0;
  int    esum = 0, neg = 0, mystep = -1;
  unsigned alive = act ? 1u : 0u;
  LUStep<0>::run(row, lane, alive, mant_prod, esum, neg, mystep);

  double logdet = log(mant_prod) + (double)esum * 0.6931471805599453;

  // permutation parity: perm[step] = lane chosen at that step
  if (mystep >= 0) perm[wave][mystep] = lane;
  __syncthreads();
  int pj  = perm[wave][act ? lane : 0];
  int inv = 0;
  for (int i = 0; i < NOCC; ++i) {
    int pi = perm[wave][i];
    inv += (act && i < lane && pi > pj) ? 1 : 0;
  }
  #pragma unroll
  for (int m = 32; m >= 1; m >>= 1) inv += __shfl_xor(inv, m, 64);

  const int sgn = ((neg + inv) & 1) ? -1 : 1;
  if (lane == 0) {
    size_t o = (((size_t)b * 2 + spin) * KDET + wave) * 2;
    dets[o]     = logdet;
    dets[o + 1] = (double)sgn;
  }
}

// PLANAR complex64 output: out[0..B) = log_abs (real), out[B..2B) = phase (imag)
__global__ __launch_bounds__(256) void combine_kernel(
    const double* __restrict__ dets, float* __restrict__ out, int B)
{
  int b = blockIdx.x * blockDim.x + threadIdx.x;
  if (b >= B) return;
  const double* du = dets + ((size_t)b * 2 + 0) * KDET * 2;
  const double* dd = dets + ((size_t)b * 2 + 1) * KDET * 2;
  double t[KDET], s[KDET], m = -1e300;
  #pragma unroll
  for (int k = 0; k < KDET; ++k) {
    t[k] = du[2 * k] + dd[2 * k];
    s[k] = du[2 * k + 1] * dd[2 * k + 1];
    if (t[k] > m) m = t[k];
  }
  double sum = 0.0;
  #pragma unroll
  for (int k = 0; k < KDET; ++k) {
    if (t[k] > -1e290) sum += s[k] * exp(t[k] - m);
  }
  double p  = (m > -1e290) ? exp(m) * fabs(sum) : 0.0;
  double la = log(p + 1e-30);                    // reproduce ref clamp exactly
  float phase = (sum >= 0.0) ? 0.0f : 3.14159265358979f;
  out[b]     = (float)la;
  out[B + b] = phase;
}

extern "C" void kernel_launch(void* const* d_in, const int* in_sizes, int n_in,
                              void* d_out, int out_size, void* d_ws, size_t ws_size,
                              hipStream_t stream) {
  const int*   configs = (const int*)  d_in[0];
  const float* tok     = (const float*)d_in[1];
  const float* pos     = (const float*)d_in[2];
  const float* W       = (const float*)d_in[3];
  const float* bv      = (const float*)d_in[4];
  double* dets = (double*)d_ws;            // needs B*2*4*2*8 = 256 KB
  const int B = in_sizes[0] / NSITE;

  dim3 grid(B, 2);
  det_kernel<<<grid, 256, 0, stream>>>(configs, tok, pos, W, bv, dets);
  combine_kernel<<<(B + 255) / 256, 256, 0, stream>>>(dets, (float*)d_out, B);
}

// Round 5
// 757.478 us; speedup vs baseline: 1.3648x; 1.1946x over previous
//
#include <hip/hip_runtime.h>
#include <math.h>

#define NSITE 100
#define NOCC  50
#define DIM   128
#define KDET  4

// readlane of a double via two 32-bit readlanes (p is wave-uniform)
__device__ __forceinline__ double readlane_d(double v, int p) {
  int lo = __builtin_amdgcn_readlane(__double2loint(v), p);
  int hi = __builtin_amdgcn_readlane(__double2hiint(v), p);
  return __hiloint2double(hi, lo);
}

// One LU pivot step with COMPILE-TIME step index J (constant row[] indices
// everywhere so SROA can promote row[] to registers; R2-R4 evidence: any
// dynamic index anywhere keeps the whole alloca in scratch -> VGPR=68,
// occupancy capped at 33%, ~900 us).
template <int J>
struct LUStep {
  static __device__ __forceinline__ void run(double (&row)[NOCC], int lane,
      unsigned& alive, double& mant_prod, int& esum, int& neg, int& mystep) {
    // pivot key: |row[J]| high-word (monotonic for abs), low 6 bits = lane
    unsigned hi  = (unsigned)__double2hiint(fabs(row[J]));
    unsigned key = alive ? ((hi & ~63u) | (unsigned)lane) : 0u;
    #pragma unroll
    for (int m = 32; m >= 1; m >>= 1) {
      unsigned o = (unsigned)__shfl_xor((int)key, m, 64);
      key = key > o ? key : o;
    }
    const int p = __builtin_amdgcn_readfirstlane((int)(key & 63u));
    const double piv = readlane_d(row[J], p);

    // piv = sign * mant * 2^(e-1023): accumulate exponent, sign, mantissa
    const unsigned phiw = (unsigned)__double2hiint(piv);
    esum += (int)((phiw >> 20) & 0x7ffu) - 1023;
    neg  += (int)(phiw >> 31);
    mant_prod *= __hiloint2double((int)((phiw & 0x000FFFFFu) | 0x3FF00000u),
                                  __double2loint(piv));

    if (lane == p) mystep = J;
    alive &= (lane != p) ? 1u : 0u;
    const double rp   = (piv != 0.0) ? 1.0 / piv : 0.0;
    const double mult = alive ? row[J] * rp : 0.0;
    #pragma unroll
    for (int cc = J + 1; cc < NOCC; ++cc) {   // compile-time bounds
      const double pc = readlane_d(row[cc], p);
      row[cc] = fma(-mult, pc, row[cc]);
    }
    LUStep<J + 1>::run(row, lane, alive, mant_prod, esum, neg, mystep);
  }
};
template <>
struct LUStep<NOCC> {
  static __device__ __forceinline__ void run(double (&)[NOCC], int,
      unsigned&, double&, int&, int&, int&) {}
};

// One block per (batch, spin). Wave w handles determinant k=w.
// Lane r owns row r of phi entirely in registers (r < 50).
__global__ __launch_bounds__(256, 2) void det_kernel(
    const int*   __restrict__ configs,   // (B,100) int32
    const float* __restrict__ tok,       // (4,128)
    const float* __restrict__ pos,       // (144,128)
    const float* __restrict__ W,         // (400,128)
    const float* __restrict__ bvec,      // (400,)
    double*      __restrict__ dets)      // (B,2,4,2)  {logdet, sign}
{
  const int b    = blockIdx.x;
  const int spin = blockIdx.y;

  __shared__ int cfg[NSITE];
  __shared__ int idx[NOCC];
  __shared__ int occl[NOCC];
  __shared__ int filll[NOCC];
  __shared__ int perm[4][NOCC];

  const int tid = threadIdx.x;
  if (tid < NSITE) cfg[tid] = configs[(size_t)b * NSITE + tid];
  __syncthreads();

  // Occupied-index list per reference argsort semantics: all occupied sites
  // (ascending, capped 50) + smallest unoccupied fill, merged sorted.
  if (tid == 0) {
    int no = 0, nf = 0;
    for (int n = 0; n < NSITE; ++n) {
      int c = cfg[n];
      bool occ = (spin == 0) ? (c == 1 || c == 3) : (c == 2 || c == 3);
      if (occ) { if (no < NOCC) occl[no++]  = n; }
      else     { if (nf < NOCC) filll[nf++] = n; }
    }
    int need = NOCC - no; if (need < 0) need = 0;
    int i = 0, j = 0;
    for (int k = 0; k < NOCC; ++k) {
      bool takeocc = (i < no) && (j >= need || occl[i] < filll[j]);
      idx[k] = takeocc ? occl[i++] : filll[j++];
    }
  }
  __syncthreads();

  const int lane = tid & 63;
  const int wave = tid >> 6;
  const int wave_u  = __builtin_amdgcn_readfirstlane(wave);
  const int colbase = spin * 200 + wave_u * 50;          // uniform
  const float* Wb = W    + (size_t)colbase * DIM;        // uniform base
  const float* bb = bvec + colbase;

  const int  r   = lane;
  const bool act = (r < NOCC);
  const int  site = idx[act ? r : 0];
  const int  c    = cfg[site];
  const float4* tok4 = (const float4*)(tok + (size_t)c    * DIM);
  const float4* pos4 = (const float4*)(pos + (size_t)site * DIM);

  // ---- GEMM (fp32): row r of phi_k = h . W[colbase+j] + b ----
  // Single 50-wide accumulator pass. Every acc[] index is constant after
  // the (small-body, fully-unrolling) jj loops -> SROA-promotable.
  float acc[NOCC];
  #pragma unroll
  for (int jj = 0; jj < NOCC; ++jj) acc[jj] = bb[jj];
  for (int d4 = 0; d4 < DIM / 4; ++d4) {
    float4 t = tok4[d4], p = pos4[d4];
    const float a0 = t.x + p.x, a1 = t.y + p.y;
    const float a2 = t.z + p.z, a3 = t.w + p.w;
    #pragma unroll
    for (int jj = 0; jj < NOCC; ++jj) {
      float4 w = ((const float4*)(Wb + (size_t)jj * DIM))[d4];
      float s = fmaf(a0, w.x, acc[jj]);
      s = fmaf(a1, w.y, s);
      s = fmaf(a2, w.z, s);
      acc[jj] = fmaf(a3, w.w, s);
    }
  }

  double row[NOCC];
  #pragma unroll
  for (int jj = 0; jj < NOCC; ++jj)
    row[jj] = act ? (double)acc[jj] : 0.0;

  // ---- LU (fp64), register-resident, fully unrolled via templates ----
  double mant_prod = 1.0;
  int    esum = 0, neg = 0, mystep = -1;
  unsigned alive = act ? 1u : 0u;
  LUStep<0>::run(row, lane, alive, mant_prod, esum, neg, mystep);

  double logdet = log(mant_prod) + (double)esum * 0.6931471805599453;

  // permutation parity: perm[step] = lane chosen at that step
  if (mystep >= 0) perm[wave][mystep] = lane;
  __syncthreads();
  int pj  = perm[wave][act ? lane : 0];
  int inv = 0;
  for (int i = 0; i < NOCC; ++i) {
    int pi = perm[wave][i];
    inv += (act && i < lane && pi > pj) ? 1 : 0;
  }
  #pragma unroll
  for (int m = 32; m >= 1; m >>= 1) inv += __shfl_xor(inv, m, 64);

  const int sgn = ((neg + inv) & 1) ? -1 : 1;
  if (lane == 0) {
    size_t o = (((size_t)b * 2 + spin) * KDET + wave) * 2;
    dets[o]     = logdet;
    dets[o + 1] = (double)sgn;
  }
}

// PLANAR complex64 output: out[0..B) = log_abs (real), out[B..2B) = phase (imag)
__global__ __launch_bounds__(256) void combine_kernel(
    const double* __restrict__ dets, float* __restrict__ out, int B)
{
  int b = blockIdx.x * blockDim.x + threadIdx.x;
  if (b >= B) return;
  const double* du = dets + ((size_t)b * 2 + 0) * KDET * 2;
  const double* dd = dets + ((size_t)b * 2 + 1) * KDET * 2;
  double t[KDET], s[KDET], m = -1e300;
  #pragma unroll
  for (int k = 0; k < KDET; ++k) {
    t[k] = du[2 * k] + dd[2 * k];
    s[k] = du[2 * k + 1] * dd[2 * k + 1];
    if (t[k] > m) m = t[k];
  }
  double sum = 0.0;
  #pragma unroll
  for (int k = 0; k < KDET; ++k) {
    if (t[k] > -1e290) sum += s[k] * exp(t[k] - m);
  }
  double p  = (m > -1e290) ? exp(m) * fabs(sum) : 0.0;
  double la = log(p + 1e-30);                    // reproduce ref clamp exactly
  float phase = (sum >= 0.0) ? 0.0f : 3.14159265358979f;
  out[b]     = (float)la;
  out[B + b] = phase;
}

extern "C" void kernel_launch(void* const* d_in, const int* in_sizes, int n_in,
                              void* d_out, int out_size, void* d_ws, size_t ws_size,
                              hipStream_t stream) {
  const int*   configs = (const int*)  d_in[0];
  const float* tok     = (const float*)d_in[1];
  const float* pos     = (const float*)d_in[2];
  const float* W       = (const float*)d_in[3];
  const float* bv      = (const float*)d_in[4];
  double* dets = (double*)d_ws;            // needs B*2*4*2*8 = 256 KB
  const int B = in_sizes[0] / NSITE;

  dim3 grid(B, 2);
  det_kernel<<<grid, 256, 0, stream>>>(configs, tok, pos, W, bv, dets);
  combine_kernel<<<(B + 255) / 256, 256, 0, stream>>>(dets, (float*)d_out, B);
}